// Round 3
// baseline (611.811 us; speedup 1.0000x reference)
//
#include <hip/hip_runtime.h>
#include <hip/hip_bf16.h>

#define HID   1024
#define S_LEN 2048
#define NB    4
#define M_TOK 8192        // NB * S_LEN
#define HEADS 16
#define DH    64
#define FFN   4096

typedef __attribute__((ext_vector_type(8))) __bf16 bf16x8;
typedef __attribute__((ext_vector_type(4))) __bf16 bf16x4;
typedef __attribute__((ext_vector_type(4))) float  f32x4;

// async global->LDS, 16B per lane, dest = wave-uniform base + lane*16
__device__ __forceinline__ void gl_lds16(const void* g, void* l) {
  __builtin_amdgcn_global_load_lds(
      (const __attribute__((address_space(1))) void*)g,
      (__attribute__((address_space(3))) void*)l, 16, 0, 0);
}

// ---------------- cast fp32 -> bf16 (vectorized) ----------------
__global__ __launch_bounds__(256)
void cast_kernel(const float* __restrict__ in, __bf16* __restrict__ out, int n4) {
  int i = blockIdx.x * 256 + threadIdx.x;
  if (i < n4) {
    float4 v = reinterpret_cast<const float4*>(in)[i];
    bf16x4 o = { (__bf16)v.x, (__bf16)v.y, (__bf16)v.z, (__bf16)v.w };
    reinterpret_cast<bf16x4*>(out)[i] = o;
  }
}

// ---------------- LayerNorm: fp32 in -> bf16 out, one block per row ----------------
__global__ __launch_bounds__(256)
void ln_kernel(const float* __restrict__ x, const float* __restrict__ g,
               const float* __restrict__ bb, __bf16* __restrict__ out) {
  const int row = blockIdx.x;
  const int tid = threadIdx.x;
  const float4 v = reinterpret_cast<const float4*>(x + (size_t)row * HID)[tid];
  float s  = v.x + v.y + v.z + v.w;
  float sq = v.x*v.x + v.y*v.y + v.z*v.z + v.w*v.w;
  #pragma unroll
  for (int o = 32; o > 0; o >>= 1) { s += __shfl_down(s, o); sq += __shfl_down(sq, o); }
  __shared__ float ls[4], lq[4];
  if ((tid & 63) == 0) { ls[tid >> 6] = s; lq[tid >> 6] = sq; }
  __syncthreads();
  s  = ls[0] + ls[1] + ls[2] + ls[3];
  sq = lq[0] + lq[1] + lq[2] + lq[3];
  const float mu   = s * (1.0f / HID);
  const float rstd = rsqrtf(sq * (1.0f / HID) - mu * mu + 1e-5f);
  const float4 gv = reinterpret_cast<const float4*>(g)[tid];
  const float4 bv = reinterpret_cast<const float4*>(bb)[tid];
  bf16x4 o;
  o[0] = (__bf16)((v.x - mu) * rstd * gv.x + bv.x);
  o[1] = (__bf16)((v.y - mu) * rstd * gv.y + bv.y);
  o[2] = (__bf16)((v.z - mu) * rstd * gv.z + bv.z);
  o[3] = (__bf16)((v.w - mu) * rstd * gv.w + bv.w);
  reinterpret_cast<bf16x4*>(out + (size_t)row * HID)[tid] = o;
}

// ---------------- GEMM: C[m,n] = sum_k A[m,k]*Bw[n,k] (+bias, epilogue variants) ----
// m97 structure: 128x128 tile, BK=64, 4 waves (2x2), global_load_lds width=16.
// T1 XCD swizzle: bid%8 -> contiguous logical chunk per XCD (nwg%8==0 for all grids).
// EPI 0: bf16 out = acc+bias ; EPI 1: bf16 out = relu(acc+bias) ;
// EPI 2: f32 out = res + acc + bias
template<int EPI>
__global__ __launch_bounds__(256)
void gemm_bt(const __bf16* __restrict__ A, const __bf16* __restrict__ Bw,
             const float* __restrict__ bias, const float* __restrict__ res,
             __bf16* __restrict__ obf, float* __restrict__ of,
             int M, int N, int K) {
  __shared__ __bf16 Al[128 * 64];
  __shared__ __bf16 Bl[128 * 64];
  const int tid  = threadIdx.x;
  const int lane = tid & 63;
  const int wid  = tid >> 6;
  const int wm = wid >> 1, wn = wid & 1;
  // T1: dispatch-id -> XCD-contiguous logical tile id (bijective; nwg % 8 == 0)
  const int nwg = gridDim.x * gridDim.y;
  const int bid = blockIdx.y * gridDim.x + blockIdx.x;
  const int swz = (bid & 7) * (nwg >> 3) + (bid >> 3);
  const long bm = (long)(swz / gridDim.x) * 128;
  const long bn = (long)(swz % gridDim.x) * 128;
  const int r8 = lane >> 3, c8 = lane & 7;

  f32x4 acc[4][4] = {};

  const int nk = K >> 6;
  for (int kt = 0; kt < nk; ++kt) {
    const int k0 = kt << 6;
    __syncthreads();               // prior tile's reads finished
    #pragma unroll
    for (int i = 0; i < 4; ++i) {
      const int rbase = i * 32 + wid * 8;
      gl_lds16(A + (bm + rbase + r8) * (long)K + k0 + c8 * 8, &Al[rbase * 64]);
    }
    #pragma unroll
    for (int i = 0; i < 4; ++i) {
      const int rbase = i * 32 + wid * 8;
      gl_lds16(Bw + (bn + rbase + r8) * (long)K + k0 + c8 * 8, &Bl[rbase * 64]);
    }
    __syncthreads();               // drains vmcnt(0): LDS tiles ready
    #pragma unroll
    for (int kk = 0; kk < 2; ++kk) {
      bf16x8 af[4], bfr[4];
      #pragma unroll
      for (int mt = 0; mt < 4; ++mt)
        af[mt] = *(const bf16x8*)&Al[(wm * 64 + mt * 16 + (lane & 15)) * 64 + kk * 32 + (lane >> 4) * 8];
      #pragma unroll
      for (int nt = 0; nt < 4; ++nt)
        bfr[nt] = *(const bf16x8*)&Bl[(wn * 64 + nt * 16 + (lane & 15)) * 64 + kk * 32 + (lane >> 4) * 8];
      #pragma unroll
      for (int mt = 0; mt < 4; ++mt)
        #pragma unroll
        for (int nt = 0; nt < 4; ++nt)
          acc[mt][nt] = __builtin_amdgcn_mfma_f32_16x16x32_bf16(af[mt], bfr[nt], acc[mt][nt], 0, 0, 0);
    }
  }

  // epilogue: D mapping col=lane&15, row=(lane>>4)*4+j  [m89/m91 verified]
  #pragma unroll
  for (int mt = 0; mt < 4; ++mt) {
    const long row0 = bm + wm * 64 + mt * 16 + ((lane >> 4) << 2);
    #pragma unroll
    for (int nt = 0; nt < 4; ++nt) {
      const long col = bn + wn * 64 + nt * 16 + (lane & 15);
      const float bsv = bias[col];
      #pragma unroll
      for (int j = 0; j < 4; ++j) {
        const float val = acc[mt][nt][j] + bsv;
        const long idx = (row0 + j) * (long)N + col;
        if (EPI == 0)      obf[idx] = (__bf16)val;
        else if (EPI == 1) obf[idx] = (__bf16)fmaxf(val, 0.0f);
        else               of[idx]  = res[idx] + val;
      }
    }
  }
}

// ---------------- Flash attention: 4 waves x 16 q-rows, kv tiles of 64 -------------
// Round-1 verified kernel; only change: grid swapped to (x=bh, y=q-tile) so all
// q-tiles of one head land on XCD bh%8 (8 heads x 512KB K/V = 4MB = one L2).
__global__ __launch_bounds__(256)
void attn_kernel(const __bf16* __restrict__ q, const __bf16* __restrict__ k,
                 const __bf16* __restrict__ v, __bf16* __restrict__ o) {
  __shared__ __bf16 Kl[64 * 64];
  __shared__ __bf16 Vt[64 * 64];      // transposed: Vt[d][kv]
  __shared__ __bf16 Pl[4 * 16 * 64];
  const int tid = threadIdx.x, lane = tid & 63, wid = tid >> 6;
  const int bh = blockIdx.x, b = bh >> 4, h = bh & 15;
  const size_t base = ((size_t)b * S_LEN) * HID + h * DH;
  const int q0 = blockIdx.y * 64 + wid * 16;
  const int r8 = lane >> 3, c8 = lane & 7;

  // Q fragments in registers, prescaled by 1/sqrt(64)=0.125 (exact pow2)
  bf16x8 qf[2];
  {
    const __bf16* qp = q + base + (size_t)(q0 + (lane & 15)) * HID + (lane >> 4) * 8;
    #pragma unroll
    for (int kk = 0; kk < 2; ++kk) {
      bf16x8 t = *(const bf16x8*)(qp + kk * 32);
      #pragma unroll
      for (int j = 0; j < 8; ++j) t[j] = (__bf16)((float)t[j] * 0.125f);
      qf[kk] = t;
    }
  }

  f32x4 oacc[4] = {};
  float mrun[4], lrun[4];
  #pragma unroll
  for (int j = 0; j < 4; ++j) { mrun[j] = -3.0e38f; lrun[j] = 0.f; }

  __bf16* pw = &Pl[wid * (16 * 64)];

  for (int kv0 = 0; kv0 < S_LEN; kv0 += 64) {
    __syncthreads();
    // stage K via global_load_lds, source pre-swizzled (linear dest, rule 21)
    #pragma unroll
    for (int i = 0; i < 2; ++i) {
      const int rbase = i * 32 + wid * 8;
      const int row = rbase + r8;
      const int k3 = (row ^ (row >> 3)) & 7;
      gl_lds16(k + base + (size_t)(kv0 + row) * HID + ((c8 ^ k3) << 3), &Kl[rbase * 64]);
    }
    // stage V transposed (coalesced 16B read, swizzled scalar LDS writes: 2-way)
    #pragma unroll
    for (int i = 0; i < 2; ++i) {
      const int r = i * 32 + (tid >> 3);
      const int d0 = c8 * 8;
      bf16x8 t = *(const bf16x8*)(v + base + (size_t)(kv0 + r) * HID + d0);
      #pragma unroll
      for (int j = 0; j < 8; ++j) {
        const int d = d0 + j;
        const int k3 = (d ^ (d >> 3)) & 7;
        Vt[d * 64 + (r ^ (k3 << 3))] = t[j];
      }
    }
    __syncthreads();

    // QK^T: scores[qi, kv] ; D row=(lane>>4)*4+j (qi), col=lane&15 (kv within ct)
    float pvv[4][4];
    #pragma unroll
    for (int ct = 0; ct < 4; ++ct) {
      f32x4 sa = {};
      const int rk = ct * 16 + (lane & 15);
      const int k3 = (rk ^ (rk >> 3)) & 7;
      #pragma unroll
      for (int kk = 0; kk < 2; ++kk) {
        bf16x8 kf = *(const bf16x8*)&Kl[rk * 64 + (((kk * 4 + (lane >> 4)) ^ k3) << 3)];
        sa = __builtin_amdgcn_mfma_f32_16x16x32_bf16(qf[kk], kf, sa, 0, 0, 0);
      }
      #pragma unroll
      for (int j = 0; j < 4; ++j) pvv[ct][j] = sa[j];
    }

    // online softmax per q-row (rows live in 16-lane groups; xor-shuffle <=8 stays in group)
    #pragma unroll
    for (int j = 0; j < 4; ++j) {
      float mx = fmaxf(fmaxf(pvv[0][j], pvv[1][j]), fmaxf(pvv[2][j], pvv[3][j]));
      #pragma unroll
      for (int off = 8; off > 0; off >>= 1) mx = fmaxf(mx, __shfl_xor(mx, off));
      const float mnew = fmaxf(mrun[j], mx);
      const float corr = __expf(mrun[j] - mnew);
      float ps = 0.f;
      #pragma unroll
      for (int ct = 0; ct < 4; ++ct) {
        const float p = __expf(pvv[ct][j] - mnew);
        pvv[ct][j] = p; ps += p;
      }
      #pragma unroll
      for (int off = 8; off > 0; off >>= 1) ps += __shfl_xor(ps, off);
      lrun[j] = lrun[j] * corr + ps;
      mrun[j] = mnew;
      #pragma unroll
      for (int dt = 0; dt < 4; ++dt) oacc[dt][j] *= corr;
    }

    // P -> LDS (wave-private region, swizzled), then PV MFMA
    #pragma unroll
    for (int ct = 0; ct < 4; ++ct) {
      #pragma unroll
      for (int j = 0; j < 4; ++j) {
        const int prow = ((lane >> 4) << 2) + j;
        const int k3 = (prow ^ (prow >> 3)) & 7;
        pw[prow * 64 + ((ct * 16 + (lane & 15)) ^ (k3 << 3))] = (__bf16)pvv[ct][j];
      }
    }
    #pragma unroll
    for (int kk = 0; kk < 2; ++kk) {
      const int pr = lane & 15;
      const int k3p = (pr ^ (pr >> 3)) & 7;
      bf16x8 pf = *(const bf16x8*)&pw[pr * 64 + (((kk * 4 + (lane >> 4)) ^ k3p) << 3)];
      #pragma unroll
      for (int dt = 0; dt < 4; ++dt) {
        const int dv = dt * 16 + (lane & 15);
        const int k3v = (dv ^ (dv >> 3)) & 7;
        bf16x8 vf = *(const bf16x8*)&Vt[dv * 64 + (((kk * 4 + (lane >> 4)) ^ k3v) << 3)];
        oacc[dt] = __builtin_amdgcn_mfma_f32_16x16x32_bf16(pf, vf, oacc[dt], 0, 0, 0);
      }
    }
  }

  // epilogue: O[qi][d] = oacc/l
  #pragma unroll
  for (int j = 0; j < 4; ++j) {
    const float inv = 1.0f / lrun[j];
    const size_t orow = base + (size_t)(q0 + ((lane >> 4) << 2) + j) * HID;
    #pragma unroll
    for (int dt = 0; dt < 4; ++dt)
      o[orow + dt * 16 + (lane & 15)] = (__bf16)(oacc[dt][j] * inv);
  }
}

// ---------------- launch ----------------
extern "C" void kernel_launch(void* const* d_in, const int* in_sizes, int n_in,
                              void* d_out, int out_size, void* d_ws, size_t ws_size,
                              hipStream_t stream) {
  (void)in_sizes; (void)n_in; (void)out_size; (void)ws_size;
  const float* x   = (const float*)d_in[0];
  const float* n1g = (const float*)d_in[1];
  const float* n1b = (const float*)d_in[2];
  const float* wq  = (const float*)d_in[3];
  const float* bq  = (const float*)d_in[4];
  const float* wk  = (const float*)d_in[5];
  const float* bk  = (const float*)d_in[6];
  const float* wv  = (const float*)d_in[7];
  const float* bv  = (const float*)d_in[8];
  const float* wo  = (const float*)d_in[9];
  const float* bo  = (const float*)d_in[10];
  const float* n2g = (const float*)d_in[11];
  const float* n2b = (const float*)d_in[12];
  const float* w1  = (const float*)d_in[13];
  const float* b1  = (const float*)d_in[14];
  const float* w2  = (const float*)d_in[15];
  const float* b2  = (const float*)d_in[16];

  char* ws = (char*)d_ws;
  const size_t MB = 1ull << 20;
  __bf16* wq_b = (__bf16*)(ws);
  __bf16* wk_b = (__bf16*)(ws + 2 * MB);
  __bf16* wv_b = (__bf16*)(ws + 4 * MB);
  __bf16* wo_b = (__bf16*)(ws + 6 * MB);
  __bf16* w1_b = (__bf16*)(ws + 8 * MB);
  __bf16* w2_b = (__bf16*)(ws + 16 * MB);
  __bf16* h1   = (__bf16*)(ws + 24 * MB);   // LN1 out; reused as attn_out
  __bf16* qb   = (__bf16*)(ws + 40 * MB);   // q; reused as h2 (LN2 out)
  __bf16* kb   = (__bf16*)(ws + 56 * MB);
  __bf16* vb   = (__bf16*)(ws + 72 * MB);
  __bf16* ffn1 = (__bf16*)(ws + 56 * MB);   // reuses k/v region after attention
  float*  x2   = (float*)(ws + 120 * MB);   // 120..152 MB

  // weights -> bf16 (every call; deterministic, ~11us)
  cast_kernel<<<1024, 256, 0, stream>>>(wq, wq_b, HID * HID / 4);
  cast_kernel<<<1024, 256, 0, stream>>>(wk, wk_b, HID * HID / 4);
  cast_kernel<<<1024, 256, 0, stream>>>(wv, wv_b, HID * HID / 4);
  cast_kernel<<<1024, 256, 0, stream>>>(wo, wo_b, HID * HID / 4);
  cast_kernel<<<4096, 256, 0, stream>>>(w1, w1_b, FFN * HID / 4);
  cast_kernel<<<4096, 256, 0, stream>>>(w2, w2_b, FFN * HID / 4);

  ln_kernel<<<M_TOK, 256, 0, stream>>>(x, n1g, n1b, h1);

  dim3 g1(HID / 128, M_TOK / 128);    // 8 x 64 = 512 blocks (nwg%8==0)
  gemm_bt<0><<<g1, 256, 0, stream>>>(h1, wq_b, bq, nullptr, qb, nullptr, M_TOK, HID, HID);
  gemm_bt<0><<<g1, 256, 0, stream>>>(h1, wk_b, bk, nullptr, kb, nullptr, M_TOK, HID, HID);
  gemm_bt<0><<<g1, 256, 0, stream>>>(h1, wv_b, bv, nullptr, vb, nullptr, M_TOK, HID, HID);

  dim3 ga(NB * HEADS, S_LEN / 64);    // x=bh (64), y=q-tile (32): head-per-XCD locality
  attn_kernel<<<ga, 256, 0, stream>>>(qb, kb, vb, h1);

  // x2 = x + attn_out @ wo^T + bo   (fp32 residual in epilogue)
  gemm_bt<2><<<g1, 256, 0, stream>>>(h1, wo_b, bo, x, nullptr, x2, M_TOK, HID, HID);

  ln_kernel<<<M_TOK, 256, 0, stream>>>(x2, n2g, n2b, qb);

  dim3 g2(FFN / 128, M_TOK / 128);    // 32 x 64 = 2048 blocks (nwg%8==0)
  gemm_bt<1><<<g2, 256, 0, stream>>>(qb, w1_b, b1, nullptr, ffn1, nullptr, M_TOK, FFN, HID);

  // out = x2 + ffn1 @ w2^T + b2
  gemm_bt<2><<<g1, 256, 0, stream>>>(ffn1, w2_b, b2, x2, nullptr, (float*)d_out, M_TOK, HID, FFN);
}

// Round 4
// 602.954 us; speedup vs baseline: 1.0147x; 1.0147x over previous
//
#include <hip/hip_runtime.h>
#include <hip/hip_bf16.h>

#define HID   1024
#define S_LEN 2048
#define NB    4
#define M_TOK 8192        // NB * S_LEN
#define HEADS 16
#define DH    64
#define FFN   4096

typedef __attribute__((ext_vector_type(8))) __bf16 bf16x8;
typedef __attribute__((ext_vector_type(4))) __bf16 bf16x4;
typedef __attribute__((ext_vector_type(4))) float  f32x4;

// async global->LDS, 16B per lane, dest = wave-uniform base + lane*16
__device__ __forceinline__ void gl_lds16(const void* g, void* l) {
  __builtin_amdgcn_global_load_lds(
      (const __attribute__((address_space(1))) void*)g,
      (__attribute__((address_space(3))) void*)l, 16, 0, 0);
}

__device__ __forceinline__ int k3f(int r) { return (r ^ (r >> 3)) & 7; }

// ---------------- cast fp32 -> bf16 (vectorized) ----------------
__global__ __launch_bounds__(256)
void cast_kernel(const float* __restrict__ in, __bf16* __restrict__ out, int n4) {
  int i = blockIdx.x * 256 + threadIdx.x;
  if (i < n4) {
    float4 v = reinterpret_cast<const float4*>(in)[i];
    bf16x4 o = { (__bf16)v.x, (__bf16)v.y, (__bf16)v.z, (__bf16)v.w };
    reinterpret_cast<bf16x4*>(out)[i] = o;
  }
}

// ---------------- LayerNorm: fp32 in -> bf16 out, one block per row ----------------
__global__ __launch_bounds__(256)
void ln_kernel(const float* __restrict__ x, const float* __restrict__ g,
               const float* __restrict__ bb, __bf16* __restrict__ out) {
  const int row = blockIdx.x;
  const int tid = threadIdx.x;
  const float4 v = reinterpret_cast<const float4*>(x + (size_t)row * HID)[tid];
  float s  = v.x + v.y + v.z + v.w;
  float sq = v.x*v.x + v.y*v.y + v.z*v.z + v.w*v.w;
  #pragma unroll
  for (int o = 32; o > 0; o >>= 1) { s += __shfl_down(s, o); sq += __shfl_down(sq, o); }
  __shared__ float ls[4], lq[4];
  if ((tid & 63) == 0) { ls[tid >> 6] = s; lq[tid >> 6] = sq; }
  __syncthreads();
  s  = ls[0] + ls[1] + ls[2] + ls[3];
  sq = lq[0] + lq[1] + lq[2] + lq[3];
  const float mu   = s * (1.0f / HID);
  const float rstd = rsqrtf(sq * (1.0f / HID) - mu * mu + 1e-5f);
  const float4 gv = reinterpret_cast<const float4*>(g)[tid];
  const float4 bv = reinterpret_cast<const float4*>(bb)[tid];
  bf16x4 o;
  o[0] = (__bf16)((v.x - mu) * rstd * gv.x + bv.x);
  o[1] = (__bf16)((v.y - mu) * rstd * gv.y + bv.y);
  o[2] = (__bf16)((v.z - mu) * rstd * gv.z + bv.z);
  o[3] = (__bf16)((v.w - mu) * rstd * gv.w + bv.w);
  reinterpret_cast<bf16x4*>(out + (size_t)row * HID)[tid] = o;
}

// ---------------- GEMM: C[m,n] = sum_k A[m,k]*Bw[n,k] (+bias, epilogue variants) ----
// m97 structure: 128x128 tile, BK=64, 4 waves (2x2), global_load_lds width=16.
// T1 XCD swizzle: bid%8 -> contiguous logical chunk per XCD (nwg%8==0 for all grids).
template<int EPI>
__global__ __launch_bounds__(256)
void gemm_bt(const __bf16* __restrict__ A, const __bf16* __restrict__ Bw,
             const float* __restrict__ bias, const float* __restrict__ res,
             __bf16* __restrict__ obf, float* __restrict__ of,
             int M, int N, int K) {
  __shared__ __bf16 Al[128 * 64];
  __shared__ __bf16 Bl[128 * 64];
  const int tid  = threadIdx.x;
  const int lane = tid & 63;
  const int wid  = tid >> 6;
  const int wm = wid >> 1, wn = wid & 1;
  const int nwg = gridDim.x * gridDim.y;
  const int bid = blockIdx.y * gridDim.x + blockIdx.x;
  const int swz = (bid & 7) * (nwg >> 3) + (bid >> 3);
  const long bm = (long)(swz / gridDim.x) * 128;
  const long bn = (long)(swz % gridDim.x) * 128;
  const int r8 = lane >> 3, c8 = lane & 7;

  f32x4 acc[4][4] = {};

  const int nk = K >> 6;
  for (int kt = 0; kt < nk; ++kt) {
    const int k0 = kt << 6;
    __syncthreads();
    #pragma unroll
    for (int i = 0; i < 4; ++i) {
      const int rbase = i * 32 + wid * 8;
      gl_lds16(A + (bm + rbase + r8) * (long)K + k0 + c8 * 8, &Al[rbase * 64]);
    }
    #pragma unroll
    for (int i = 0; i < 4; ++i) {
      const int rbase = i * 32 + wid * 8;
      gl_lds16(Bw + (bn + rbase + r8) * (long)K + k0 + c8 * 8, &Bl[rbase * 64]);
    }
    __syncthreads();
    #pragma unroll
    for (int kk = 0; kk < 2; ++kk) {
      bf16x8 af[4], bfr[4];
      #pragma unroll
      for (int mt = 0; mt < 4; ++mt)
        af[mt] = *(const bf16x8*)&Al[(wm * 64 + mt * 16 + (lane & 15)) * 64 + kk * 32 + (lane >> 4) * 8];
      #pragma unroll
      for (int nt = 0; nt < 4; ++nt)
        bfr[nt] = *(const bf16x8*)&Bl[(wn * 64 + nt * 16 + (lane & 15)) * 64 + kk * 32 + (lane >> 4) * 8];
      #pragma unroll
      for (int mt = 0; mt < 4; ++mt)
        #pragma unroll
        for (int nt = 0; nt < 4; ++nt)
          acc[mt][nt] = __builtin_amdgcn_mfma_f32_16x16x32_bf16(af[mt], bfr[nt], acc[mt][nt], 0, 0, 0);
    }
  }

  #pragma unroll
  for (int mt = 0; mt < 4; ++mt) {
    const long row0 = bm + wm * 64 + mt * 16 + ((lane >> 4) << 2);
    #pragma unroll
    for (int nt = 0; nt < 4; ++nt) {
      const long col = bn + wn * 64 + nt * 16 + (lane & 15);
      const float bsv = bias[col];
      #pragma unroll
      for (int j = 0; j < 4; ++j) {
        const float val = acc[mt][nt][j] + bsv;
        const long idx = (row0 + j) * (long)N + col;
        if (EPI == 0)      obf[idx] = (__bf16)val;
        else if (EPI == 1) obf[idx] = (__bf16)fmaxf(val, 0.0f);
        else               of[idx]  = res[idx] + val;
      }
    }
  }
}

// ---------------- Flash attention: swapped QK^T, verified 16x16x32 layouts only ----
// 4 waves x 32 q-rows (2 groups of 16). Per 64-kv tile:
//   sacc[ct] = mfma(A=K_rows, B=Q) -> lane owns P[q=lane&15][kv=16ct+4hi4+j]
//   softmax: in-register over 16 + shfl_xor(16,32); corr moved to O-rows via 4 shfl
//   P -> LDS as bf16x4 vector writes (kv contiguous), read back as A-fragments
//   PV: mfma(A=P, B=Vt-reads) identical to round-1's verified pattern.
__global__ __launch_bounds__(256)
void attn_kernel(const __bf16* __restrict__ q, const __bf16* __restrict__ k,
                 const __bf16* __restrict__ v, __bf16* __restrict__ o) {
  __shared__ __bf16 Kl[64 * 64];
  __shared__ __bf16 Vt[64 * 64];         // transposed: Vt[d][kv], chunk-swizzled
  __shared__ __bf16 Pl[4 * 16 * 72];     // per-wave P: [q 16][kv 64] stride 72
  const int tid = threadIdx.x, lane = tid & 63, wid = tid >> 6;
  const int q15 = lane & 15, hi4 = lane >> 4;      // hi4 in 0..3
  const int bh = blockIdx.x, b = bh >> 4, h = bh & 15;
  const size_t base = ((size_t)b * S_LEN) * HID + h * DH;
  const int q0 = blockIdx.y * 128 + wid * 32;      // wave's 32 q rows; group g: +16g
  const int r8 = lane >> 3, c8 = lane & 7;

  // Q B-fragments: qf[g][kk] elem j = Q[q0+16g+q15][32kk + 8hi4 + j] * 0.125
  bf16x8 qf[2][2];
  #pragma unroll
  for (int g = 0; g < 2; ++g) {
    const __bf16* qp = q + base + (size_t)(q0 + 16 * g + q15) * HID + hi4 * 8;
    #pragma unroll
    for (int kk = 0; kk < 2; ++kk) {
      bf16x8 t = *(const bf16x8*)(qp + kk * 32);
      #pragma unroll
      for (int j = 0; j < 8; ++j) t[j] = (__bf16)((float)t[j] * 0.125f);
      qf[g][kk] = t;
    }
  }

  f32x4 oacc[2][4] = {};
  float mrun[2] = { -3.0e38f, -3.0e38f }, lrun[2] = { 0.f, 0.f };
  __bf16* pb = &Pl[wid * (16 * 72)];

  for (int kv0 = 0; kv0 < S_LEN; kv0 += 64) {
    __syncthreads();
    // stage K via global_load_lds, source pre-swizzled (linear dest, rule 21)
    #pragma unroll
    for (int i = 0; i < 2; ++i) {
      const int rbase = i * 32 + wid * 8;
      const int row = rbase + r8;
      gl_lds16(k + base + (size_t)(kv0 + row) * HID + ((c8 ^ k3f(row)) << 3), &Kl[rbase * 64]);
    }
    // stage V transposed (coalesced 16B read, chunk-swizzled scalar LDS writes)
    #pragma unroll
    for (int i = 0; i < 2; ++i) {
      const int r = i * 32 + (tid >> 3);
      const int d0 = c8 * 8;
      bf16x8 t = *(const bf16x8*)(v + base + (size_t)(kv0 + r) * HID + d0);
      #pragma unroll
      for (int j = 0; j < 8; ++j) {
        const int d = d0 + j;
        Vt[d * 64 + (r ^ (k3f(d) << 3))] = t[j];
      }
    }
    __syncthreads();

    #pragma unroll
    for (int g = 0; g < 2; ++g) {
      // ---- swapped QK^T: sacc[ct] = K-rows x Q; lane owns q = q15
      f32x4 sacc[4] = {};
      #pragma unroll
      for (int ct = 0; ct < 4; ++ct) {
        const int rk = ct * 16 + q15;
        const int k3 = k3f(rk);
        #pragma unroll
        for (int kk = 0; kk < 2; ++kk) {
          bf16x8 kf = *(const bf16x8*)&Kl[rk * 64 + (((kk * 4 + hi4) ^ k3) << 3)];
          sacc[ct] = __builtin_amdgcn_mfma_f32_16x16x32_bf16(kf, qf[g][kk], sacc[ct], 0, 0, 0);
        }
      }
      // lane holds P[q15][kv = 16ct + 4hi4 + jj] in sacc[ct][jj]
      float pv[16];
      #pragma unroll
      for (int ct = 0; ct < 4; ++ct)
        #pragma unroll
        for (int jj = 0; jj < 4; ++jj) pv[ct * 4 + jj] = sacc[ct][jj];

      // ---- softmax (state at q = q15 lanes; 2+2 shuffles total)
      float mx = pv[0];
      #pragma unroll
      for (int i = 1; i < 16; ++i) mx = fmaxf(mx, pv[i]);
      mx = fmaxf(mx, __shfl_xor(mx, 16));
      mx = fmaxf(mx, __shfl_xor(mx, 32));
      const float mnew = fmaxf(mrun[g], mx);
      const float corr = __expf(mrun[g] - mnew);
      float ps = 0.f;
      #pragma unroll
      for (int i = 0; i < 16; ++i) { pv[i] = __expf(pv[i] - mnew); ps += pv[i]; }
      ps += __shfl_xor(ps, 16);
      ps += __shfl_xor(ps, 32);
      lrun[g] = lrun[g] * corr + ps;
      mrun[g] = mnew;

      // ---- P -> LDS (vector bf16x4 writes, kv contiguous per lane)
      #pragma unroll
      for (int ct = 0; ct < 4; ++ct) {
        bf16x4 w;
        #pragma unroll
        for (int jj = 0; jj < 4; ++jj) w[jj] = (__bf16)pv[ct * 4 + jj];
        *(bf16x4*)&pb[q15 * 72 + ct * 16 + hi4 * 4] = w;
      }

      // ---- rescale O accumulator (corr transported to O-row owners)
      #pragma unroll
      for (int jj = 0; jj < 4; ++jj) {
        const float cO = __shfl(corr, (hi4 << 4) | (hi4 * 4 + jj));
        #pragma unroll
        for (int dt = 0; dt < 4; ++dt) oacc[g][dt][jj] *= cO;
      }

      // ---- PV: oacc[g][dt] += P x V  (A = P from LDS, B = Vt reads, both verified)
      #pragma unroll
      for (int kk = 0; kk < 2; ++kk) {
        bf16x8 pf = *(const bf16x8*)&pb[q15 * 72 + kk * 32 + hi4 * 8];
        #pragma unroll
        for (int dt = 0; dt < 4; ++dt) {
          const int dv = dt * 16 + q15;
          bf16x8 vf = *(const bf16x8*)&Vt[dv * 64 + (((kk * 4 + hi4) ^ k3f(dv)) << 3)];
          oacc[g][dt] = __builtin_amdgcn_mfma_f32_16x16x32_bf16(pf, vf, oacc[g][dt], 0, 0, 0);
        }
      }
    }
  }

  // ---- epilogue: O[q = q0+16g+4hi4+jj][d = dt*16+q15]
  #pragma unroll
  for (int g = 0; g < 2; ++g) {
    const float inv = 1.0f / lrun[g];
    #pragma unroll
    for (int jj = 0; jj < 4; ++jj) {
      const float iO = __shfl(inv, (hi4 << 4) | (hi4 * 4 + jj));
      const size_t orow = base + (size_t)(q0 + 16 * g + hi4 * 4 + jj) * HID;
      #pragma unroll
      for (int dt = 0; dt < 4; ++dt)
        o[orow + dt * 16 + q15] = (__bf16)(oacc[g][dt][jj] * iO);
    }
  }
}

// ---------------- launch ----------------
extern "C" void kernel_launch(void* const* d_in, const int* in_sizes, int n_in,
                              void* d_out, int out_size, void* d_ws, size_t ws_size,
                              hipStream_t stream) {
  (void)in_sizes; (void)n_in; (void)out_size; (void)ws_size;
  const float* x   = (const float*)d_in[0];
  const float* n1g = (const float*)d_in[1];
  const float* n1b = (const float*)d_in[2];
  const float* wq  = (const float*)d_in[3];
  const float* bq  = (const float*)d_in[4];
  const float* wk  = (const float*)d_in[5];
  const float* bk  = (const float*)d_in[6];
  const float* wv  = (const float*)d_in[7];
  const float* bv  = (const float*)d_in[8];
  const float* wo  = (const float*)d_in[9];
  const float* bo  = (const float*)d_in[10];
  const float* n2g = (const float*)d_in[11];
  const float* n2b = (const float*)d_in[12];
  const float* w1  = (const float*)d_in[13];
  const float* b1  = (const float*)d_in[14];
  const float* w2  = (const float*)d_in[15];
  const float* b2  = (const float*)d_in[16];

  char* ws = (char*)d_ws;
  const size_t MB = 1ull << 20;
  __bf16* wq_b = (__bf16*)(ws);
  __bf16* wk_b = (__bf16*)(ws + 2 * MB);
  __bf16* wv_b = (__bf16*)(ws + 4 * MB);
  __bf16* wo_b = (__bf16*)(ws + 6 * MB);
  __bf16* w1_b = (__bf16*)(ws + 8 * MB);
  __bf16* w2_b = (__bf16*)(ws + 16 * MB);
  __bf16* h1   = (__bf16*)(ws + 24 * MB);   // LN1 out; reused as attn_out
  __bf16* qb   = (__bf16*)(ws + 40 * MB);   // q; reused as h2 (LN2 out)
  __bf16* kb   = (__bf16*)(ws + 56 * MB);
  __bf16* vb   = (__bf16*)(ws + 72 * MB);
  __bf16* ffn1 = (__bf16*)(ws + 56 * MB);   // reuses k/v region after attention
  float*  x2   = (float*)(ws + 120 * MB);   // 120..152 MB

  cast_kernel<<<1024, 256, 0, stream>>>(wq, wq_b, HID * HID / 4);
  cast_kernel<<<1024, 256, 0, stream>>>(wk, wk_b, HID * HID / 4);
  cast_kernel<<<1024, 256, 0, stream>>>(wv, wv_b, HID * HID / 4);
  cast_kernel<<<1024, 256, 0, stream>>>(wo, wo_b, HID * HID / 4);
  cast_kernel<<<4096, 256, 0, stream>>>(w1, w1_b, FFN * HID / 4);
  cast_kernel<<<4096, 256, 0, stream>>>(w2, w2_b, FFN * HID / 4);

  ln_kernel<<<M_TOK, 256, 0, stream>>>(x, n1g, n1b, h1);

  dim3 g1(HID / 128, M_TOK / 128);    // 8 x 64 = 512 blocks (nwg%8==0)
  gemm_bt<0><<<g1, 256, 0, stream>>>(h1, wq_b, bq, nullptr, qb, nullptr, M_TOK, HID, HID);
  gemm_bt<0><<<g1, 256, 0, stream>>>(h1, wk_b, bk, nullptr, kb, nullptr, M_TOK, HID, HID);
  gemm_bt<0><<<g1, 256, 0, stream>>>(h1, wv_b, bv, nullptr, vb, nullptr, M_TOK, HID, HID);

  dim3 ga(NB * HEADS, S_LEN / 128);   // x=bh (64), y=16 q-tiles: head-per-XCD locality
  attn_kernel<<<ga, 256, 0, stream>>>(qb, kb, vb, h1);

  // x2 = x + attn_out @ wo^T + bo   (fp32 residual in epilogue)
  gemm_bt<2><<<g1, 256, 0, stream>>>(h1, wo_b, bo, x, nullptr, x2, M_TOK, HID, HID);

  ln_kernel<<<M_TOK, 256, 0, stream>>>(x2, n2g, n2b, qb);

  dim3 g2(FFN / 128, M_TOK / 128);    // 32 x 64 = 2048 blocks (nwg%8==0)
  gemm_bt<1><<<g2, 256, 0, stream>>>(qb, w1_b, b1, nullptr, ffn1, nullptr, M_TOK, FFN, HID);

  // out = x2 + ffn1 @ w2^T + b2
  gemm_bt<2><<<g1, 256, 0, stream>>>(ffn1, w2_b, b2, x2, nullptr, (float*)d_out, M_TOK, HID, FFN);
}

// Round 5
// 525.716 us; speedup vs baseline: 1.1638x; 1.1469x over previous
//
#include <hip/hip_runtime.h>
#include <hip/hip_bf16.h>

#define HID   1024
#define S_LEN 2048
#define NB    4
#define M_TOK 8192        // NB * S_LEN
#define HEADS 16
#define DH    64
#define FFN   4096

typedef __attribute__((ext_vector_type(8))) __bf16 bf16x8;
typedef __attribute__((ext_vector_type(4))) __bf16 bf16x4;
typedef __attribute__((ext_vector_type(4))) float  f32x4;

// async global->LDS, 16B per lane, dest = wave-uniform base + lane*16
__device__ __forceinline__ void gl_lds16(const void* g, void* l) {
  __builtin_amdgcn_global_load_lds(
      (const __attribute__((address_space(1))) void*)g,
      (__attribute__((address_space(3))) void*)l, 16, 0, 0);
}

__device__ __forceinline__ int k3f(int r) { return (r ^ (r >> 3)) & 7; }

// ---------------- cast fp32 -> bf16 (vectorized) ----------------
__global__ __launch_bounds__(256)
void cast_kernel(const float* __restrict__ in, __bf16* __restrict__ out, int n4) {
  int i = blockIdx.x * 256 + threadIdx.x;
  if (i < n4) {
    float4 v = reinterpret_cast<const float4*>(in)[i];
    bf16x4 o = { (__bf16)v.x, (__bf16)v.y, (__bf16)v.z, (__bf16)v.w };
    reinterpret_cast<bf16x4*>(out)[i] = o;
  }
}

// ---------------- LayerNorm: fp32 in -> bf16 out, one block per row ----------------
__global__ __launch_bounds__(256)
void ln_kernel(const float* __restrict__ x, const float* __restrict__ g,
               const float* __restrict__ bb, __bf16* __restrict__ out) {
  const int row = blockIdx.x;
  const int tid = threadIdx.x;
  const float4 v = reinterpret_cast<const float4*>(x + (size_t)row * HID)[tid];
  float s  = v.x + v.y + v.z + v.w;
  float sq = v.x*v.x + v.y*v.y + v.z*v.z + v.w*v.w;
  #pragma unroll
  for (int o = 32; o > 0; o >>= 1) { s += __shfl_down(s, o); sq += __shfl_down(sq, o); }
  __shared__ float ls[4], lq[4];
  if ((tid & 63) == 0) { ls[tid >> 6] = s; lq[tid >> 6] = sq; }
  __syncthreads();
  s  = ls[0] + ls[1] + ls[2] + ls[3];
  sq = lq[0] + lq[1] + lq[2] + lq[3];
  const float mu   = s * (1.0f / HID);
  const float rstd = rsqrtf(sq * (1.0f / HID) - mu * mu + 1e-5f);
  const float4 gv = reinterpret_cast<const float4*>(g)[tid];
  const float4 bv = reinterpret_cast<const float4*>(bb)[tid];
  bf16x4 o;
  o[0] = (__bf16)((v.x - mu) * rstd * gv.x + bv.x);
  o[1] = (__bf16)((v.y - mu) * rstd * gv.y + bv.y);
  o[2] = (__bf16)((v.z - mu) * rstd * gv.z + bv.z);
  o[3] = (__bf16)((v.w - mu) * rstd * gv.w + bv.w);
  reinterpret_cast<bf16x4*>(out + (size_t)row * HID)[tid] = o;
}

// ---------------- GEMM: C[m,n] = sum_k A[m,k]*Bw[n,k] (+bias, epilogue variants) ----
// m97 structure: 128x128 tile, BK=64, 4 waves (2x2), global_load_lds width=16.
// T1 XCD swizzle: bid%8 -> contiguous logical chunk per XCD (nwg%8==0 for all grids).
template<int EPI>
__global__ __launch_bounds__(256)
void gemm_bt(const __bf16* __restrict__ A, const __bf16* __restrict__ Bw,
             const float* __restrict__ bias, const float* __restrict__ res,
             __bf16* __restrict__ obf, float* __restrict__ of,
             int M, int N, int K) {
  __shared__ __bf16 Al[128 * 64];
  __shared__ __bf16 Bl[128 * 64];
  const int tid  = threadIdx.x;
  const int lane = tid & 63;
  const int wid  = tid >> 6;
  const int wm = wid >> 1, wn = wid & 1;
  const int nwg = gridDim.x * gridDim.y;
  const int bid = blockIdx.y * gridDim.x + blockIdx.x;
  const int swz = (bid & 7) * (nwg >> 3) + (bid >> 3);
  const long bm = (long)(swz / gridDim.x) * 128;
  const long bn = (long)(swz % gridDim.x) * 128;
  const int r8 = lane >> 3, c8 = lane & 7;

  f32x4 acc[4][4] = {};

  const int nk = K >> 6;
  for (int kt = 0; kt < nk; ++kt) {
    const int k0 = kt << 6;
    __syncthreads();
    #pragma unroll
    for (int i = 0; i < 4; ++i) {
      const int rbase = i * 32 + wid * 8;
      gl_lds16(A + (bm + rbase + r8) * (long)K + k0 + c8 * 8, &Al[rbase * 64]);
    }
    #pragma unroll
    for (int i = 0; i < 4; ++i) {
      const int rbase = i * 32 + wid * 8;
      gl_lds16(Bw + (bn + rbase + r8) * (long)K + k0 + c8 * 8, &Bl[rbase * 64]);
    }
    __syncthreads();
    #pragma unroll
    for (int kk = 0; kk < 2; ++kk) {
      bf16x8 af[4], bfr[4];
      #pragma unroll
      for (int mt = 0; mt < 4; ++mt)
        af[mt] = *(const bf16x8*)&Al[(wm * 64 + mt * 16 + (lane & 15)) * 64 + kk * 32 + (lane >> 4) * 8];
      #pragma unroll
      for (int nt = 0; nt < 4; ++nt)
        bfr[nt] = *(const bf16x8*)&Bl[(wn * 64 + nt * 16 + (lane & 15)) * 64 + kk * 32 + (lane >> 4) * 8];
      #pragma unroll
      for (int mt = 0; mt < 4; ++mt)
        #pragma unroll
        for (int nt = 0; nt < 4; ++nt)
          acc[mt][nt] = __builtin_amdgcn_mfma_f32_16x16x32_bf16(af[mt], bfr[nt], acc[mt][nt], 0, 0, 0);
    }
  }

  #pragma unroll
  for (int mt = 0; mt < 4; ++mt) {
    const long row0 = bm + wm * 64 + mt * 16 + ((lane >> 4) << 2);
    #pragma unroll
    for (int nt = 0; nt < 4; ++nt) {
      const long col = bn + wn * 64 + nt * 16 + (lane & 15);
      const float bsv = bias[col];
      #pragma unroll
      for (int j = 0; j < 4; ++j) {
        const float val = acc[mt][nt][j] + bsv;
        const long idx = (row0 + j) * (long)N + col;
        if (EPI == 0)      obf[idx] = (__bf16)val;
        else if (EPI == 1) obf[idx] = (__bf16)fmaxf(val, 0.0f);
        else               of[idx]  = res[idx] + val;
      }
    }
  }
}

// ---------------- Flash attention: swapped QK^T, 16 q-rows/wave, 2048 blocks ------
// Round-4 softmax structure (lane owns a full q-row slice -> 4 shuffles/tile) with
// round-3 parallelism (1 q-group/wave: ~85 VGPR, 64 q/block, grid 64x32).
__global__ __launch_bounds__(256)
void attn_kernel(const __bf16* __restrict__ q, const __bf16* __restrict__ k,
                 const __bf16* __restrict__ v, __bf16* __restrict__ o) {
  __shared__ __bf16 Kl[64 * 64];
  __shared__ __bf16 Vt[64 * 64];         // transposed: Vt[d][kv], chunk-swizzled
  __shared__ __bf16 Pl[4 * 16 * 72];     // per-wave P: [q 16][kv 64] stride 72
  const int tid = threadIdx.x, lane = tid & 63, wid = tid >> 6;
  const int q15 = lane & 15, hi4 = lane >> 4;      // hi4 in 0..3
  const int bh = blockIdx.x, b = bh >> 4, h = bh & 15;
  const size_t base = ((size_t)b * S_LEN) * HID + h * DH;
  const int q0 = blockIdx.y * 64 + wid * 16;       // wave's 16 q rows
  const int r8 = lane >> 3, c8 = lane & 7;

  // Q B-fragment: qf[kk] elem j = Q[q0+q15][32kk + 8hi4 + j] * 0.125
  bf16x8 qf[2];
  {
    const __bf16* qp = q + base + (size_t)(q0 + q15) * HID + hi4 * 8;
    #pragma unroll
    for (int kk = 0; kk < 2; ++kk) {
      bf16x8 t = *(const bf16x8*)(qp + kk * 32);
      #pragma unroll
      for (int j = 0; j < 8; ++j) t[j] = (__bf16)((float)t[j] * 0.125f);
      qf[kk] = t;
    }
  }

  f32x4 oacc[4] = {};
  float mrun = -3.0e38f, lrun = 0.f;
  __bf16* pb = &Pl[wid * (16 * 72)];

  for (int kv0 = 0; kv0 < S_LEN; kv0 += 64) {
    __syncthreads();
    // stage K via global_load_lds, source pre-swizzled (linear dest, rule 21)
    #pragma unroll
    for (int i = 0; i < 2; ++i) {
      const int rbase = i * 32 + wid * 8;
      const int row = rbase + r8;
      gl_lds16(k + base + (size_t)(kv0 + row) * HID + ((c8 ^ k3f(row)) << 3), &Kl[rbase * 64]);
    }
    // stage V transposed (coalesced 16B read, chunk-swizzled scalar LDS writes)
    #pragma unroll
    for (int i = 0; i < 2; ++i) {
      const int r = i * 32 + (tid >> 3);
      const int d0 = c8 * 8;
      bf16x8 t = *(const bf16x8*)(v + base + (size_t)(kv0 + r) * HID + d0);
      #pragma unroll
      for (int j = 0; j < 8; ++j) {
        const int d = d0 + j;
        Vt[d * 64 + (r ^ (k3f(d) << 3))] = t[j];
      }
    }
    __syncthreads();

    // ---- swapped QK^T: sacc[ct] = K-rows x Q; lane owns q = q15
    f32x4 sacc[4] = {};
    __builtin_amdgcn_s_setprio(1);
    #pragma unroll
    for (int ct = 0; ct < 4; ++ct) {
      const int rk = ct * 16 + q15;
      const int k3 = k3f(rk);
      #pragma unroll
      for (int kk = 0; kk < 2; ++kk) {
        bf16x8 kf = *(const bf16x8*)&Kl[rk * 64 + (((kk * 4 + hi4) ^ k3) << 3)];
        sacc[ct] = __builtin_amdgcn_mfma_f32_16x16x32_bf16(kf, qf[kk], sacc[ct], 0, 0, 0);
      }
    }
    __builtin_amdgcn_s_setprio(0);

    // lane holds P[q15][kv = 16ct + 4hi4 + jj] in sacc[ct][jj]
    float pv[16];
    #pragma unroll
    for (int ct = 0; ct < 4; ++ct)
      #pragma unroll
      for (int jj = 0; jj < 4; ++jj) pv[ct * 4 + jj] = sacc[ct][jj];

    // ---- softmax (state at q = q15 lanes; 2+2 shuffles total)
    float mx = pv[0];
    #pragma unroll
    for (int i = 1; i < 16; ++i) mx = fmaxf(mx, pv[i]);
    mx = fmaxf(mx, __shfl_xor(mx, 16));
    mx = fmaxf(mx, __shfl_xor(mx, 32));
    const float mnew = fmaxf(mrun, mx);
    const float corr = __expf(mrun - mnew);
    float ps = 0.f;
    #pragma unroll
    for (int i = 0; i < 16; ++i) { pv[i] = __expf(pv[i] - mnew); ps += pv[i]; }
    ps += __shfl_xor(ps, 16);
    ps += __shfl_xor(ps, 32);
    lrun = lrun * corr + ps;
    mrun = mnew;

    // ---- P -> LDS (vector bf16x4 writes, kv contiguous per lane)
    #pragma unroll
    for (int ct = 0; ct < 4; ++ct) {
      bf16x4 w;
      #pragma unroll
      for (int jj = 0; jj < 4; ++jj) w[jj] = (__bf16)pv[ct * 4 + jj];
      *(bf16x4*)&pb[q15 * 72 + ct * 16 + hi4 * 4] = w;
    }

    // ---- rescale O accumulator (corr transported to O-row owners)
    #pragma unroll
    for (int jj = 0; jj < 4; ++jj) {
      const float cO = __shfl(corr, (hi4 << 4) | (hi4 * 4 + jj));
      #pragma unroll
      for (int dt = 0; dt < 4; ++dt) oacc[dt][jj] *= cO;
    }

    // ---- PV: oacc[dt] += P x V  (A = P from LDS, B = Vt reads)
    __builtin_amdgcn_s_setprio(1);
    #pragma unroll
    for (int kk = 0; kk < 2; ++kk) {
      bf16x8 pf = *(const bf16x8*)&pb[q15 * 72 + kk * 32 + hi4 * 8];
      #pragma unroll
      for (int dt = 0; dt < 4; ++dt) {
        const int dv = dt * 16 + q15;
        bf16x8 vf = *(const bf16x8*)&Vt[dv * 64 + (((kk * 4 + hi4) ^ k3f(dv)) << 3)];
        oacc[dt] = __builtin_amdgcn_mfma_f32_16x16x32_bf16(pf, vf, oacc[dt], 0, 0, 0);
      }
    }
    __builtin_amdgcn_s_setprio(0);
  }

  // ---- epilogue: O[q = q0+4hi4+jj][d = dt*16+q15]
  const float inv = 1.0f / lrun;
  #pragma unroll
  for (int jj = 0; jj < 4; ++jj) {
    const float iO = __shfl(inv, (hi4 << 4) | (hi4 * 4 + jj));
    const size_t orow = base + (size_t)(q0 + hi4 * 4 + jj) * HID;
    #pragma unroll
    for (int dt = 0; dt < 4; ++dt)
      o[orow + dt * 16 + q15] = (__bf16)(oacc[dt][jj] * iO);
  }
}

// ---------------- launch ----------------
extern "C" void kernel_launch(void* const* d_in, const int* in_sizes, int n_in,
                              void* d_out, int out_size, void* d_ws, size_t ws_size,
                              hipStream_t stream) {
  (void)in_sizes; (void)n_in; (void)out_size; (void)ws_size;
  const float* x   = (const float*)d_in[0];
  const float* n1g = (const float*)d_in[1];
  const float* n1b = (const float*)d_in[2];
  const float* wq  = (const float*)d_in[3];
  const float* bq  = (const float*)d_in[4];
  const float* wk  = (const float*)d_in[5];
  const float* bk  = (const float*)d_in[6];
  const float* wv  = (const float*)d_in[7];
  const float* bv  = (const float*)d_in[8];
  const float* wo  = (const float*)d_in[9];
  const float* bo  = (const float*)d_in[10];
  const float* n2g = (const float*)d_in[11];
  const float* n2b = (const float*)d_in[12];
  const float* w1  = (const float*)d_in[13];
  const float* b1  = (const float*)d_in[14];
  const float* w2  = (const float*)d_in[15];
  const float* b2  = (const float*)d_in[16];

  char* ws = (char*)d_ws;
  const size_t MB = 1ull << 20;
  __bf16* wq_b = (__bf16*)(ws);
  __bf16* wk_b = (__bf16*)(ws + 2 * MB);
  __bf16* wv_b = (__bf16*)(ws + 4 * MB);
  __bf16* wo_b = (__bf16*)(ws + 6 * MB);
  __bf16* w1_b = (__bf16*)(ws + 8 * MB);
  __bf16* w2_b = (__bf16*)(ws + 16 * MB);
  __bf16* h1   = (__bf16*)(ws + 24 * MB);   // LN1 out; reused as attn_out
  __bf16* qb   = (__bf16*)(ws + 40 * MB);   // q; reused as h2 (LN2 out)
  __bf16* kb   = (__bf16*)(ws + 56 * MB);
  __bf16* vb   = (__bf16*)(ws + 72 * MB);
  __bf16* ffn1 = (__bf16*)(ws + 56 * MB);   // reuses k/v region after attention
  float*  x2   = (float*)(ws + 120 * MB);   // 120..152 MB

  cast_kernel<<<1024, 256, 0, stream>>>(wq, wq_b, HID * HID / 4);
  cast_kernel<<<1024, 256, 0, stream>>>(wk, wk_b, HID * HID / 4);
  cast_kernel<<<1024, 256, 0, stream>>>(wv, wv_b, HID * HID / 4);
  cast_kernel<<<1024, 256, 0, stream>>>(wo, wo_b, HID * HID / 4);
  cast_kernel<<<4096, 256, 0, stream>>>(w1, w1_b, FFN * HID / 4);
  cast_kernel<<<4096, 256, 0, stream>>>(w2, w2_b, FFN * HID / 4);

  ln_kernel<<<M_TOK, 256, 0, stream>>>(x, n1g, n1b, h1);

  dim3 g1(HID / 128, M_TOK / 128);    // 8 x 64 = 512 blocks (nwg%8==0)
  gemm_bt<0><<<g1, 256, 0, stream>>>(h1, wq_b, bq, nullptr, qb, nullptr, M_TOK, HID, HID);
  gemm_bt<0><<<g1, 256, 0, stream>>>(h1, wk_b, bk, nullptr, kb, nullptr, M_TOK, HID, HID);
  gemm_bt<0><<<g1, 256, 0, stream>>>(h1, wv_b, bv, nullptr, vb, nullptr, M_TOK, HID, HID);

  dim3 ga(NB * HEADS, S_LEN / 64);    // x=bh (64), y=32 q-tiles: head-per-XCD locality
  attn_kernel<<<ga, 256, 0, stream>>>(qb, kb, vb, h1);

  // x2 = x + attn_out @ wo^T + bo   (fp32 residual in epilogue)
  gemm_bt<2><<<g1, 256, 0, stream>>>(h1, wo_b, bo, x, nullptr, x2, M_TOK, HID, HID);

  ln_kernel<<<M_TOK, 256, 0, stream>>>(x2, n2g, n2b, qb);

  dim3 g2(FFN / 128, M_TOK / 128);    // 32 x 64 = 2048 blocks (nwg%8==0)
  gemm_bt<1><<<g2, 256, 0, stream>>>(qb, w1_b, b1, nullptr, ffn1, nullptr, M_TOK, FFN, HID);

  // out = x2 + ffn1 @ w2^T + b2
  gemm_bt<2><<<g1, 256, 0, stream>>>(ffn1, w2_b, b2, x2, nullptr, (float*)d_out, M_TOK, HID, FFN);
}